// Round 16
// baseline (3956.387 us; speedup 1.0000x reference)
//
#include <hip/hip_runtime.h>
#include <cstdint>
#include <cstddef>

// ECPEC pipeline for MI355X (gfx950).
// f32 for the amplified alpha path; split-bf16 MFMA (hi+lo, ~1e-5 rel err)
// for gates/s1/z2/z3 GEMMs. R16: LSTM k-loop unroll 4->16 (more outstanding
// L2 loads, identical FMA order); F+B gate GEMMs fused into one launch (z=2).

#define DEV __device__ __forceinline__
typedef float f32x4 __attribute__((ext_vector_type(4)));
typedef __bf16 bf16;
typedef bf16 bf16x8 __attribute__((ext_vector_type(8)));

// ---------------------------------------------------------------- f32 GEMM (small/amplified paths)
struct G32 {
    const float* A;
    const float* B;
    float* out;
    const float* bias;
    int M, N, K, lda, ldb, ldc;
};

template <int EPI>  // 0: acc(+bias?) ; 2: lrelu(acc+bias)
__global__ __launch_bounds__(512) void k_gemm32(G32 p) {
    __shared__ __align__(16) float As[32][132];
    __shared__ __align__(16) float Bs[32][132];
    const int tid = threadIdx.x;
    const int tx = tid & 15, ty = tid >> 4;
    const int m0 = blockIdx.y * 128, n0 = blockIdx.x * 128;
    float acc[4][8] = {};
    const int ra = tid >> 2;
    const int ka = (tid & 3) * 8;

    const float* arow = p.A + (size_t)(m0 + ra) * p.lda;
    const float* brow = p.B + (size_t)(n0 + ra) * p.ldb;

    auto load_tile = [&](int kt, float* av, float* bv) {
        const float* ap = arow + kt + ka;
#pragma unroll
        for (int q = 0; q < 8; q++) av[q] = ap[q];
        const float* bp = brow + kt + ka;
#pragma unroll
        for (int q = 0; q < 8; q++) bv[q] = bp[q];
    };

    const int nt = p.K / 32;
    float av[8], bv[8];
    load_tile(0, av, bv);
    for (int t = 0; t < nt; t++) {
        __syncthreads();
#pragma unroll
        for (int q = 0; q < 8; q++) {
            As[ka + q][ra] = av[q];
            Bs[ka + q][ra] = bv[q];
        }
        __syncthreads();
        if (t + 1 < nt) load_tile((t + 1) * 32, av, bv);
#pragma unroll
        for (int kk = 0; kk < 32; kk++) {
            float a[4], b[8];
            *(f32x4*)a = *(const f32x4*)&As[kk][ty * 4];
            *(f32x4*)b = *(const f32x4*)&Bs[kk][tx * 4];
            *(f32x4*)(b + 4) = *(const f32x4*)&Bs[kk][64 + tx * 4];
#pragma unroll
            for (int i = 0; i < 4; i++)
#pragma unroll
                for (int j = 0; j < 8; j++) acc[i][j] += a[i] * b[j];
        }
    }

#pragma unroll
    for (int i = 0; i < 4; i++)
#pragma unroll
        for (int j = 0; j < 8; j++) {
            int m = m0 + ty * 4 + i;
            int n = n0 + ((j < 4) ? tx * 4 + j : 64 + tx * 4 + (j - 4));
            float x = acc[i][j];
            if constexpr (EPI == 0) {
                if (p.bias) x += p.bias[n];
            } else if constexpr (EPI == 2) {
                x += p.bias[n];
                x = x > 0.f ? x : 0.01f * x;
            }
            p.out[(size_t)m * p.ldc + n] = x;
        }
}

// ---------------------------------------------------------------- split-bf16 MFMA GEMM
// C = A @ B^T, A/B split hi/lo bf16: ab ~= AhBh + AlBh + AhBl (f32 acc).
// Tile 128x128, BK=32, 256 threads (4 waves 2x2), 4x4 16x16x32 frags.
// AMODE: 0 plain f32 A (lda=768) ; 2 A=E[e]*Cu[j] ; 4 phase-2 fold ;
//        5 fused gate GEMM (blockIdx.z: 0=fwd, 1=rev; second ptr set)
// EPI: 1 acc+bias ; 3 score partials [M][12] ; 4 phase-2 ; 5 phase-3
struct GSP {
    const float* srcA;
    const bf16* BH;
    const bf16* BL;
    float* out;
    const float* bias;
    const bf16* BH2;     // AMODE 5 (z=1)
    const bf16* BL2;
    float* out2;
    const float* bias2;
    const float* s2v;
    float* escoreP;      // [M][12] (EPI 3)
    const float* addE;
    const float* addB;
    const float* nrm;
    const float* wn;
    const float* feat;
    const float* wx;
    const float* ce;
    const float* CuEf;
    const float* pos;
    const int* slen;
    int K, ldb, ldc, c0;
};

template <int AMODE, int EPI>
__global__ __launch_bounds__(256) void k_gemm_sp(GSP p) {
    __shared__ __align__(16) bf16 AhS[128 * 32];
    __shared__ __align__(16) bf16 AlS[128 * 32];
    __shared__ __align__(16) bf16 BhS[128 * 32];
    __shared__ __align__(16) bf16 BlS[128 * 32];
    const int tid = threadIdx.x;
    const int lane = tid & 63;
    const int w = tid >> 6;
    const int wm = w >> 1, wn_ = w & 1;
    const int m0 = blockIdx.y * 128, n0 = blockIdx.x * 128;
    const int l15 = lane & 15, lq = lane >> 4;
    const int dz = (AMODE == 5) ? blockIdx.z : 0;

    const bf16* BHp = (AMODE == 5 && dz) ? p.BH2 : p.BH;
    const bf16* BLp = (AMODE == 5 && dz) ? p.BL2 : p.BL;
    const float* biasp = (AMODE == 5 && dz) ? p.bias2 : p.bias;
    float* outp = (AMODE == 5 && dz) ? p.out2 : p.out;

    f32x4 zero4 = {0.f, 0.f, 0.f, 0.f};
    f32x4 acc[4][4];
#pragma unroll
    for (int i = 0; i < 4; i++)
#pragma unroll
        for (int j = 0; j < 4; j++) acc[i][j] = zero4;

    const int c0s = tid, c1s = tid + 256;
    const int ar0 = c0s >> 2, ao0 = (c0s & 3) << 3;
    const int ar1 = c1s >> 2, ao1 = (c1s & 3) << 3;
    const int gm0 = m0 + ar0, gm1 = m0 + ar1;

    const float* arow0 = nullptr;
    const float* arow1 = nullptr;
    const float *er0 = nullptr, *cr0 = nullptr, *pr0 = nullptr;
    const float *er1 = nullptr, *cr1 = nullptr, *pr1 = nullptr;
    if constexpr (AMODE == 0) {
        arow0 = p.srcA + (size_t)gm0 * 768;
        arow1 = p.srcA + (size_t)gm1 * 768;
    } else if constexpr (AMODE == 5) {
        int b0 = gm0 >> 5, t0 = p.c0 + (gm0 & 31);
        int b1 = gm1 >> 5, t1 = p.c0 + (gm1 & 31);
        if (dz) {
            int len0 = p.slen[b0], len1 = p.slen[b1];
            t0 = (t0 < len0) ? len0 - 1 - t0 : t0;
            t1 = (t1 < len1) ? len1 - 1 - t1 : t1;
        }
        arow0 = p.srcA + ((size_t)b0 * 96 + t0) * 768;
        arow1 = p.srcA + ((size_t)b1 * 96 + t1) * 768;
    } else if constexpr (AMODE == 2) {
        er0 = p.CuEf + (size_t)(256 + (gm0 >> 8)) * 768;
        cr0 = p.CuEf + (size_t)(gm0 & 255) * 768;
        er1 = p.CuEf + (size_t)(256 + (gm1 >> 8)) * 768;
        cr1 = p.CuEf + (size_t)(gm1 & 255) * 768;
    } else {
        er0 = p.CuEf + (size_t)(256 + (gm0 >> 6)) * 768;
        cr0 = p.ce + (size_t)gm0 * 768;
        pr0 = p.pos + (size_t)gm0 * 50;
        er1 = p.CuEf + (size_t)(256 + (gm1 >> 6)) * 768;
        cr1 = p.ce + (size_t)gm1 * 768;
        pr1 = p.pos + (size_t)gm1 * 50;
    }
    const bf16* bh0 = BHp + (size_t)(n0 + ar0) * p.ldb;
    const bf16* bl0 = BLp + (size_t)(n0 + ar0) * p.ldb;
    const bf16* bh1 = BHp + (size_t)(n0 + ar1) * p.ldb;
    const bf16* bl1 = BLp + (size_t)(n0 + ar1) * p.ldb;

    auto loadA = [&](int kt, int ao, const float* arow, const float* er,
                     const float* cr, const float* pr, float* a) {
        if constexpr (AMODE == 0 || AMODE == 5) {
#pragma unroll
            for (int q = 0; q < 8; q++) a[q] = arow[kt + ao + q];
        } else if constexpr (AMODE == 2) {
#pragma unroll
            for (int q = 0; q < 8; q++) a[q] = er[kt + ao + q] * cr[kt + ao + q];
        } else {
#pragma unroll
            for (int q = 0; q < 8; q++) {
                int k = kt + ao + q;
                float v;
                if (k < 768) v = cr[k];
                else if (k < 1536) v = er[k - 768] * cr[k - 768];
                else if (k < 1586) v = pr[k - 1536];
                else v = 0.f;
                a[q] = v;
            }
        }
    };

    const int nt = p.K / 32;
    float a0f[8], a1f[8];
    bf16x8 b0h, b0l, b1h, b1l;
    auto load_tile = [&](int kt) {
        loadA(kt, ao0, arow0, er0, cr0, pr0, a0f);
        loadA(kt, ao1, arow1, er1, cr1, pr1, a1f);
        b0h = *(const bf16x8*)(bh0 + kt + ao0);
        b0l = *(const bf16x8*)(bl0 + kt + ao0);
        b1h = *(const bf16x8*)(bh1 + kt + ao1);
        b1l = *(const bf16x8*)(bl1 + kt + ao1);
    };

    load_tile(0);
    for (int t = 0; t < nt; t++) {
        __syncthreads();
        {
            bf16x8 h8, l8;
#pragma unroll
            for (int q = 0; q < 8; q++) {
                bf16 h = (bf16)a0f[q];
                h8[q] = h;
                l8[q] = (bf16)(a0f[q] - (float)h);
            }
            *(bf16x8*)(AhS + (c0s << 3)) = h8;
            *(bf16x8*)(AlS + (c0s << 3)) = l8;
#pragma unroll
            for (int q = 0; q < 8; q++) {
                bf16 h = (bf16)a1f[q];
                h8[q] = h;
                l8[q] = (bf16)(a1f[q] - (float)h);
            }
            *(bf16x8*)(AhS + (c1s << 3)) = h8;
            *(bf16x8*)(AlS + (c1s << 3)) = l8;
            *(bf16x8*)(BhS + (c0s << 3)) = b0h;
            *(bf16x8*)(BlS + (c0s << 3)) = b0l;
            *(bf16x8*)(BhS + (c1s << 3)) = b1h;
            *(bf16x8*)(BlS + (c1s << 3)) = b1l;
        }
        __syncthreads();
        if (t + 1 < nt) load_tile((t + 1) * 32);

        bf16x8 ah[4], bh[4], xl[4];
#pragma unroll
        for (int i = 0; i < 4; i++) {
            ah[i] = *(const bf16x8*)(AhS + (wm * 64 + i * 16 + l15) * 32 + (lq << 3));
            bh[i] = *(const bf16x8*)(BhS + (wn_ * 64 + i * 16 + l15) * 32 + (lq << 3));
        }
#pragma unroll
        for (int i = 0; i < 4; i++)
#pragma unroll
            for (int j = 0; j < 4; j++)
                acc[i][j] = __builtin_amdgcn_mfma_f32_16x16x32_bf16(ah[i], bh[j], acc[i][j], 0, 0, 0);
#pragma unroll
        for (int i = 0; i < 4; i++)
            xl[i] = *(const bf16x8*)(AlS + (wm * 64 + i * 16 + l15) * 32 + (lq << 3));
#pragma unroll
        for (int i = 0; i < 4; i++)
#pragma unroll
            for (int j = 0; j < 4; j++)
                acc[i][j] = __builtin_amdgcn_mfma_f32_16x16x32_bf16(xl[i], bh[j], acc[i][j], 0, 0, 0);
#pragma unroll
        for (int i = 0; i < 4; i++)
            xl[i] = *(const bf16x8*)(BlS + (wn_ * 64 + i * 16 + l15) * 32 + (lq << 3));
#pragma unroll
        for (int i = 0; i < 4; i++)
#pragma unroll
            for (int j = 0; j < 4; j++)
                acc[i][j] = __builtin_amdgcn_mfma_f32_16x16x32_bf16(ah[i], xl[j], acc[i][j], 0, 0, 0);
    }

    if constexpr (EPI == 3) {
#pragma unroll
        for (int i = 0; i < 4; i++)
#pragma unroll
            for (int r = 0; r < 4; r++) {
                float s = 0.f;
#pragma unroll
                for (int j = 0; j < 4; j++) {
                    int n = n0 + wn_ * 64 + j * 16 + l15;
                    float v = acc[i][j][r] + biasp[n];
                    v = v > 0.f ? v : 0.01f * v;
                    s += v * p.s2v[n];
                }
                s += __shfl_xor(s, 1);
                s += __shfl_xor(s, 2);
                s += __shfl_xor(s, 4);
                s += __shfl_xor(s, 8);
                if (l15 == 0) {
                    int m = m0 + wm * 64 + i * 16 + (lq << 2) + r;
                    p.escoreP[(size_t)m * 12 + blockIdx.x * 2 + wn_] = s;
                }
            }
    } else {
#pragma unroll
        for (int i = 0; i < 4; i++)
#pragma unroll
            for (int j = 0; j < 4; j++)
#pragma unroll
                for (int r = 0; r < 4; r++) {
                    int m = m0 + wm * 64 + i * 16 + (lq << 2) + r;
                    int n = n0 + wn_ * 64 + j * 16 + l15;
                    float v = acc[i][j][r];
                    if constexpr (EPI == 1) {
                        v += biasp[n];
                    } else if constexpr (EPI == 4) {
                        int e = m >> 6;
                        v += p.addE[(size_t)e * 768 + n] + p.nrm[m] * p.wn[n] + p.bias[n];
                    } else if constexpr (EPI == 5) {
                        int e = m >> 8, jj = m & 255;
                        float ex = p.feat[e * 64 + (jj >> 2)];
                        v += p.addE[(size_t)e * 768 + n] + p.addB[(size_t)jj * 768 + n] +
                             p.nrm[m] * p.wn[n] + ex * p.wx[n];
                    }
                    outp[(size_t)m * p.ldc + n] = v;
                }
    }
}

// ---------------------------------------------------------------- Whh pack
__global__ void k_wpack(const float* __restrict__ whh, float* __restrict__ wp) {
    int idx = blockIdx.x * 256 + threadIdx.x;
    if (idx < 384 * 1536) {
        int k = idx / 1536, rem = idx - k * 1536;
        int u = rem >> 2, g = rem & 3;
        wp[idx] = whh[(size_t)(g * 384 + u) * 384 + k];
    }
}

// ---------------------------------------------------------------- LSTM rows
// 384 threads (thread = unit u), 4 rows of ONE direction, 32 steps, h in LDS,
// c in registers, no inter-block sync. k-loop unroll 16 for deep load hoisting
// (identical per-accumulator FMA order). dir = blockIdx&1 (XCD L2 wp affinity).
__global__ __launch_bounds__(384) void k_lstm_rows(
    const float* __restrict__ gchF, const float* __restrict__ gchB,
    const float* __restrict__ wpF, const float* __restrict__ wpB,
    float* __restrict__ hbuf, float* __restrict__ cbuf, float* __restrict__ Hs,
    const int* __restrict__ slen, int c0) {
    __shared__ __align__(16) float hlds[4][384];
    const int tid = threadIdx.x;
    const int dir = blockIdx.x & 1;
    const int r0 = (blockIdx.x >> 1) * 4;
    const float* gch = dir ? gchB : gchF;
    const float* wp = dir ? wpB : wpF;
    float* hb = hbuf + (size_t)dir * 98304;
    float* cb = cbuf + (size_t)dir * 98304;
    const int u = tid;

    {
        int r = tid / 96, c4 = (tid - r * 96) * 4;
        *(f32x4*)&hlds[r][c4] = *(const f32x4*)&hb[(size_t)(r0 + r) * 384 + c4];
    }
    float c_[4];
    int len_[4];
#pragma unroll
    for (int r = 0; r < 4; r++) {
        c_[r] = cb[(size_t)(r0 + r) * 384 + u];
        len_[r] = slen[r0 + r];
    }
    __syncthreads();

    const float* wpb = wp + (size_t)u * 4;
    for (int t = c0; t < c0 + 32; t++) {
        float acc[4][4] = {};
#pragma unroll 16
        for (int k = 0; k < 384; k++) {
            f32x4 wv = *(const f32x4*)(wpb + (size_t)k * 1536);
            float h0 = hlds[0][k], h1 = hlds[1][k];
            float h2 = hlds[2][k], h3 = hlds[3][k];
#pragma unroll
            for (int g = 0; g < 4; g++) {
                acc[0][g] += h0 * wv[g];
                acc[1][g] += h1 * wv[g];
                acc[2][g] += h2 * wv[g];
                acc[3][g] += h3 * wv[g];
            }
        }
        __syncthreads();
#pragma unroll
        for (int r = 0; r < 4; r++) {
            int bg = r0 + r;
            int len = len_[r];
            int tsrc = dir ? (t < len ? len - 1 - t : t) : t;
            const float* gp = gch + (((size_t)bg << 5) + (t & 31)) * 1536;
            float gi = acc[r][0] + gp[u];
            float gf = acc[r][1] + gp[384 + u];
            float gg2 = acc[r][2] + gp[768 + u];
            float go = acc[r][3] + gp[1152 + u];
            float si = 1.f / (1.f + __expf(-gi));
            float sf = 1.f / (1.f + __expf(-gf));
            float so = 1.f / (1.f + __expf(-go));
            float tg = tanhf(gg2);
            float cn = sf * c_[r] + si * tg;
            float hn = so * tanhf(cn);
            c_[r] = cn;
            hlds[r][u] = hn;
            int tpos = dir ? tsrc : t;
            Hs[((size_t)bg * 96 + tpos) * 768 + dir * 384 + u] = hn;
        }
        __syncthreads();
    }

    {
        int r = tid / 96, c4 = (tid - r * 96) * 4;
        *(f32x4*)&hb[(size_t)(r0 + r) * 384 + c4] = *(const f32x4*)&hlds[r][c4];
    }
#pragma unroll
    for (int r = 0; r < 4; r++) cb[(size_t)(r0 + r) * 384 + u] = c_[r];
}

// ---------------------------------------------------------------- small kernels
__global__ void k_bias2(const float* a, const float* b, float* o, int n) {
    int i = blockIdx.x * 256 + threadIdx.x;
    if (i < n) o[i] = a[i] + b[i];
}

__global__ void k_splitw(const float* __restrict__ src, bf16* __restrict__ hi,
                         bf16* __restrict__ lo, int n) {
    int i = blockIdx.x * 256 + threadIdx.x;
    if (i < n) {
        float v = src[i];
        bf16 h = (bf16)v;
        hi[i] = h;
        lo[i] = (bf16)(v - (float)h);
    }
}

__global__ __launch_bounds__(256) void k_transp32(const float* __restrict__ src,
                                                  float* __restrict__ dst, int roff) {
    __shared__ float tile[32][33];
    int tx = threadIdx.x & 31, ty = threadIdx.x >> 5;
    int n0 = blockIdx.x * 32, k0 = blockIdx.y * 32;
#pragma unroll
    for (int r = ty; r < 32; r += 8)
        tile[r][tx] = src[(size_t)(roff + k0 + r) * 768 + n0 + tx];
    __syncthreads();
#pragma unroll
    for (int r = ty; r < 32; r += 8)
        dst[(size_t)(n0 + r) * 768 + k0 + tx] = tile[tx][r];
}

__global__ __launch_bounds__(256) void k_transp_sp(const float* __restrict__ src,
                                                   bf16* __restrict__ hi,
                                                   bf16* __restrict__ lo, int roff) {
    __shared__ float tile[32][33];
    int tx = threadIdx.x & 31, ty = threadIdx.x >> 5;
    int n0 = blockIdx.x * 32, k0 = blockIdx.y * 32;
#pragma unroll
    for (int r = ty; r < 32; r += 8)
        tile[r][tx] = src[(size_t)(roff + k0 + r) * 768 + n0 + tx];
    __syncthreads();
#pragma unroll
    for (int r = ty; r < 32; r += 8) {
        float v = tile[tx][r];
        bf16 h = (bf16)v;
        hi[(size_t)(n0 + r) * 768 + k0 + tx] = h;
        lo[(size_t)(n0 + r) * 768 + k0 + tx] = (bf16)(v - (float)h);
    }
}

__global__ __launch_bounds__(256) void k_b2cat_sp(const float* __restrict__ W2,
                                                  bf16* __restrict__ hi,
                                                  bf16* __restrict__ lo) {
    __shared__ float tile[32][33];
    int tx = threadIdx.x & 31, ty = threadIdx.x >> 5;
    int n0 = blockIdx.x * 32, k0 = blockIdx.y * 32;
#pragma unroll
    for (int r = ty; r < 32; r += 8) {
        int k = k0 + r;
        float v = 0.f;
        if (k < 1586) {
            int sr = (k < 768) ? 768 + k : 769 + k;
            v = W2[(size_t)sr * 768 + n0 + tx];
        }
        tile[r][tx] = v;
    }
    __syncthreads();
#pragma unroll
    for (int r = ty; r < 32; r += 8) {
        float v = tile[tx][r];
        bf16 h = (bf16)v;
        hi[(size_t)(n0 + r) * 1600 + k0 + tx] = h;
        lo[(size_t)(n0 + r) * 1600 + k0 + tx] = (bf16)(v - (float)h);
    }
}

// alpha = e*mask / (sum + 1e-9); U[b,:] = sum_t alpha[t]*Hs[b,t,:]
__global__ __launch_bounds__(256) void k_alpha_u(const float* __restrict__ escoreP,
                                                 const float* __restrict__ Hs,
                                                 const int* __restrict__ slen,
                                                 float* __restrict__ U) {
    __shared__ float al[96];
    __shared__ float dsh;
    int b = blockIdx.x, tid = threadIdx.x;
    int len = slen[b];
    if (tid < 96) {
        const float* ep = escoreP + (size_t)(b * 96 + tid) * 12;
        float e = 0.f;
#pragma unroll
        for (int q = 0; q < 12; q++) e += ep[q];
        al[tid] = (tid < len) ? e : 0.f;
    }
    __syncthreads();
    if (tid == 0) {
        float s = 0.f;
        for (int i = 0; i < 96; i++) s += al[i];
        dsh = 1.f / (s + 1e-9f);
    }
    __syncthreads();
    float dinv = dsh;
    for (int d = tid; d < 768; d += 256) {
        float acc = 0.f;
        const float* hp = Hs + (size_t)b * 96 * 768 + d;
        for (int tt = 0; tt < 96; tt++) acc += al[tt] * hp[(size_t)tt * 768];
        U[(size_t)b * 768 + d] = acc * dinv;
    }
}

__global__ void k_ucat(const float* __restrict__ U, const int* __restrict__ cau,
                       const int* __restrict__ emo, float* __restrict__ Ucat) {
    int i = blockIdx.x * 256 + threadIdx.x;
    if (i < 384 * 768) {
        int r = i / 768, d = i - r * 768;
        int src = (r < 256) ? cau[r] : emo[r - 256];
        Ucat[i] = U[(size_t)src * 768 + d];
    }
}

__global__ __launch_bounds__(256) void k_chunk_sc(const float* __restrict__ CuEf,
                                                  float* __restrict__ sc) {
    int m = blockIdx.x;
    int e = m >> 6, nk = m & 63;
    int tid = threadIdx.x, w = tid >> 6, lane = tid & 63;
    const float* Er = CuEf + (size_t)(256 + e) * 768;
    const float* Cr = CuEf + (size_t)(nk * 4 + w) * 768;
    float acc = 0.f;
    for (int q = lane; q < 768; q += 64) acc += Er[q] * Cr[q];
    for (int off = 32; off; off >>= 1) acc += __shfl_xor(acc, off);
    __shared__ float S[4];
    if (lane == 0) S[w] = acc;
    __syncthreads();
    if (tid == 0) {
        float mx = fmaxf(fmaxf(S[0], S[1]), fmaxf(S[2], S[3]));
        float e0 = expf(S[0] - mx), e1 = expf(S[1] - mx), e2 = expf(S[2] - mx),
              e3 = expf(S[3] - mx);
        float inv = 1.f / (e0 + e1 + e2 + e3);
        sc[4 * m] = e0 * inv; sc[4 * m + 1] = e1 * inv;
        sc[4 * m + 2] = e2 * inv; sc[4 * m + 3] = e3 * inv;
    }
}

__global__ void k_chunk_emb(const float* __restrict__ sc, const float* __restrict__ CuEf,
                            float* __restrict__ ce) {
    int i = blockIdx.x * 256 + threadIdx.x;
    if (i < 8192 * 768) {
        int m = i / 768, d = i - m * 768;
        int nk = m & 63;
        const float* base = CuEf + (size_t)(nk * 4) * 768 + d;
        ce[i] = sc[4 * m] * base[0] + sc[4 * m + 1] * base[768] +
                sc[4 * m + 2] * base[1536] + sc[4 * m + 3] * base[2304];
    }
}

__global__ __launch_bounds__(256) void k_nrm2(const float* __restrict__ ce,
                                              const float* __restrict__ CuEf,
                                              float* __restrict__ nrm2) {
    int m = blockIdx.x, tid = threadIdx.x;
    int e = m >> 6;
    const float* cr = ce + (size_t)m * 768;
    const float* er = CuEf + (size_t)(256 + e) * 768;
    float ss = 0.f;
    for (int d = tid; d < 768; d += 256) {
        float df = er[d] - cr[d];
        ss += df * df;
    }
    for (int off = 32; off; off >>= 1) ss += __shfl_xor(ss, off);
    __shared__ float red[4];
    if ((tid & 63) == 0) red[tid >> 6] = ss;
    __syncthreads();
    if (tid == 0) nrm2[m] = sqrtf(red[0] + red[1] + red[2] + red[3]);
}

__global__ __launch_bounds__(256) void k_nrm3(const float* __restrict__ CuEf,
                                              float* __restrict__ nrm3) {
    int m = blockIdx.x, tid = threadIdx.x;
    int e = m >> 8, j = m & 255;
    const float* cu = CuEf + (size_t)j * 768;
    const float* er = CuEf + (size_t)(256 + e) * 768;
    float ss = 0.f;
    for (int d = tid; d < 768; d += 256) {
        float df = er[d] - cu[d];
        ss += df * df;
    }
    for (int off = 32; off; off >>= 1) ss += __shfl_xor(ss, off);
    __shared__ float red[4];
    if ((tid & 63) == 0) red[tid >> 6] = ss;
    __syncthreads();
    if (tid == 0) nrm3[m] = sqrtf(red[0] + red[1] + red[2] + red[3]);
}

__global__ void k_bv3_dis(float* __restrict__ Bv3, const float* __restrict__ dis,
                          const float* __restrict__ W3, const float* __restrict__ b3) {
    int i = blockIdx.x * 256 + threadIdx.x;
    if (i < 256 * 768) {
        int j = i / 768, n = i - j * 768;
        float s = Bv3[i] + b3[n];
        const float* dr = dis + j * 50;
#pragma unroll 10
        for (int q = 0; q < 50; q++) s += dr[q] * W3[(size_t)(2305 + q) * 768 + n];
        Bv3[i] = s;
    }
}

template <int GROUP>
__global__ __launch_bounds__(256) void k_bnstats(const float* __restrict__ z,
                                                 float* __restrict__ mean,
                                                 float* __restrict__ rstd) {
    int idx = blockIdx.x * 256 + threadIdx.x;
    if (idx >= 128 * 768) return;
    int e = idx / 768, n = idx - e * 768;
    const float* p = z + (size_t)e * GROUP * 768 + n;
    float s = 0.f;
    for (int k = 0; k < GROUP; k++) s += p[(size_t)k * 768];
    float mu = s * (1.f / GROUP);
    float q = 0.f;
    for (int k = 0; k < GROUP; k++) {
        float d = p[(size_t)k * 768] - mu;
        q += d * d;
    }
    mean[idx] = mu;
    rstd[idx] = rsqrtf(q * (1.f / GROUP) + 1e-5f);
}

template <int GROUP>
__global__ __launch_bounds__(256) void k_bn_head(const float* __restrict__ z,
                                                 const float* __restrict__ mean,
                                                 const float* __restrict__ rstd,
                                                 const float* __restrict__ W,
                                                 const float* __restrict__ bb,
                                                 float* __restrict__ outp,
                                                 float* __restrict__ feat) {
    int m = blockIdx.x;
    int e = m / GROUP;
    int tid = threadIdx.x;
    float a0 = 0.f, a1 = 0.f;
    const float* zr = z + (size_t)m * 768;
    const float* mr = mean + (size_t)e * 768;
    const float* rr = rstd + (size_t)e * 768;
    for (int n = tid; n < 768; n += 256) {
        float h = (zr[n] - mr[n]) * rr[n];
        h = h > 0.f ? h : 0.01f * h;
        a0 += h * W[2 * n];
        a1 += h * W[2 * n + 1];
    }
    for (int off = 32; off; off >>= 1) {
        a0 += __shfl_xor(a0, off);
        a1 += __shfl_xor(a1, off);
    }
    __shared__ float s0[4], s1v[4];
    int w = tid >> 6;
    if ((tid & 63) == 0) { s0[w] = a0; s1v[w] = a1; }
    __syncthreads();
    if (tid == 0) {
        float l0 = s0[0] + s0[1] + s0[2] + s0[3] + bb[0];
        float l1 = s1v[0] + s1v[1] + s1v[2] + s1v[3] + bb[1];
        float mx = fmaxf(l0, l1);
        float ls = mx + logf(expf(l0 - mx) + expf(l1 - mx));
        outp[2 * m] = l0 - ls;
        outp[2 * m + 1] = l1 - ls;
        if (feat) feat[m] = (l1 > l0) ? 1.f : 0.f;
    }
}

__global__ void k_label(const int* __restrict__ l3, float* __restrict__ out) {
    int e = blockIdx.x, c = threadIdx.x;
    int a = l3[e * 3], b = l3[e * 3 + 1], d = l3[e * 3 + 2];
    out[e * 256 + c] = (a == c || b == c || d == c) ? 1.f : 0.f;
}

// ---------------------------------------------------------------- host
extern "C" void kernel_launch(void* const* d_in, const int* in_sizes, int n_in,
                              void* d_out, int out_size, void* d_ws, size_t ws_size,
                              hipStream_t stream) {
    (void)in_sizes; (void)n_in; (void)out_size; (void)ws_size;
    const float* word = (const float*)d_in[0];
    const float* pos = (const float*)d_in[1];
    const float* dis = (const float*)d_in[2];
    const float* WihF = (const float*)d_in[3];
    const float* WhhF = (const float*)d_in[4];
    const float* bihF = (const float*)d_in[5];
    const float* bhhF = (const float*)d_in[6];
    const float* WihB = (const float*)d_in[7];
    const float* WhhB = (const float*)d_in[8];
    const float* bihB = (const float*)d_in[9];
    const float* bhhB = (const float*)d_in[10];
    const float* s1W = (const float*)d_in[11];
    const float* s1b = (const float*)d_in[12];
    const float* s2W = (const float*)d_in[13];
    const float* repW = (const float*)d_in[14];
    const float* repb = (const float*)d_in[15];
    const float* W2W = (const float*)d_in[16];
    const float* W2b = (const float*)d_in[17];
    const float* WoW = (const float*)d_in[18];
    const float* Wob = (const float*)d_in[19];
    const float* W3W = (const float*)d_in[20];
    const float* W3b = (const float*)d_in[21];
    const float* clsW = (const float*)d_in[22];
    const float* clsb = (const float*)d_in[23];
    const int* slen = (const int*)d_in[24];
    const int* emo = (const int*)d_in[25];
    const int* cau = (const int*)d_in[26];
    const int* lab3 = (const int*)d_in[27];
    float* out = (float*)d_out;

    char* ws = (char*)d_ws;
    size_t off = 0;
    auto alloc = [&](size_t b) -> char* {
        char* p = ws + off;
        off += (b + 255) & ~(size_t)255;
        return p;
    };
    float* biasF = (float*)alloc(1536 * 4);
    float* biasB = (float*)alloc(1536 * 4);
    float* wpF = (float*)alloc((size_t)384 * 1536 * 4);
    float* wpB = (float*)alloc((size_t)384 * 1536 * 4);
    bf16* wihFH = (bf16*)alloc((size_t)1536 * 768 * 2);
    bf16* wihFL = (bf16*)alloc((size_t)1536 * 768 * 2);
    bf16* wihBH = (bf16*)alloc((size_t)1536 * 768 * 2);
    bf16* wihBL = (bf16*)alloc((size_t)1536 * 768 * 2);
    bf16* s1H = (bf16*)alloc((size_t)768 * 768 * 2);
    bf16* s1L = (bf16*)alloc((size_t)768 * 768 * 2);
    bf16* B2H = (bf16*)alloc((size_t)768 * 1600 * 2);
    bf16* B2L = (bf16*)alloc((size_t)768 * 1600 * 2);
    bf16* W3dH = (bf16*)alloc((size_t)768 * 768 * 2);
    bf16* W3dL = (bf16*)alloc((size_t)768 * 768 * 2);
    float* repT = (float*)alloc((size_t)768 * 768 * 4);
    float* W2aT = (float*)alloc((size_t)768 * 768 * 4);
    float* W3aT = (float*)alloc((size_t)768 * 768 * 4);
    float* W3bT = (float*)alloc((size_t)768 * 768 * 4);
    float* hbuf = (float*)alloc((size_t)2 * 98304 * 4);
    float* cbuf = (float*)alloc((size_t)2 * 98304 * 4);
    float* Hsf = (float*)alloc((size_t)24576 * 768 * 4);
    float* escoreP = (float*)alloc((size_t)24576 * 12 * 4);
    float* Uf = (float*)alloc((size_t)256 * 768 * 4);
    float* UcatF = (float*)alloc((size_t)384 * 768 * 4);
    float* CuEf = (float*)alloc((size_t)384 * 768 * 4);
    float* scF = (float*)alloc((size_t)8192 * 4 * 4);
    float* nrm2F = (float*)alloc(8192 * 4);
    float* nrm3F = (float*)alloc(32768 * 4);
    float* E2F = (float*)alloc((size_t)128 * 768 * 4);
    float* E3F = (float*)alloc((size_t)128 * 768 * 4);
    float* Bv3F = (float*)alloc((size_t)256 * 768 * 4);
    float* mean2 = (float*)alloc((size_t)128 * 768 * 4);
    float* rstd2 = (float*)alloc((size_t)128 * 768 * 4);
    float* mean3 = (float*)alloc((size_t)128 * 768 * 4);
    float* rstd3 = (float*)alloc((size_t)128 * 768 * 4);
    float* outfeatF = (float*)alloc(8192 * 4);
    char* BIG = alloc((size_t)103 * 1024 * 1024);

    float* gchF = (float*)BIG;
    float* gchB = (float*)(BIG + (size_t)50331648);
    float* ceF = (float*)BIG;
    float* z2F = (float*)(BIG + (size_t)25165824);
    float* z3F = (float*)BIG;

    // ---- init h0 = c0 = 0
    hipMemsetAsync(hbuf, 0, (size_t)4 * 98304 * 4, stream);

    // ---- weight prep
    k_bias2<<<6, 256, 0, stream>>>(bihF, bhhF, biasF, 1536);
    k_bias2<<<6, 256, 0, stream>>>(bihB, bhhB, biasB, 1536);
    k_wpack<<<2304, 256, 0, stream>>>(WhhF, wpF);
    k_wpack<<<2304, 256, 0, stream>>>(WhhB, wpB);
    k_splitw<<<4608, 256, 0, stream>>>(WihF, wihFH, wihFL, 1536 * 768);
    k_splitw<<<4608, 256, 0, stream>>>(WihB, wihBH, wihBL, 1536 * 768);
    k_transp_sp<<<dim3(24, 24), 256, 0, stream>>>(s1W, s1H, s1L, 0);
    k_transp32<<<dim3(24, 24), 256, 0, stream>>>(repW, repT, 0);
    k_transp32<<<dim3(24, 24), 256, 0, stream>>>(W2W, W2aT, 0);
    k_transp32<<<dim3(24, 24), 256, 0, stream>>>(W3W, W3aT, 0);
    k_transp32<<<dim3(24, 24), 256, 0, stream>>>(W3W, W3bT, 768);
    k_transp_sp<<<dim3(24, 24), 256, 0, stream>>>(W3W, W3dH, W3dL, 1537);
    k_b2cat_sp<<<dim3(24, 50), 256, 0, stream>>>(W2W, B2H, B2L);

    // ---- LSTM: 3 chunks {1 fused F+B gate GEMM + 1 sync-free row kernel}
    for (int c = 0; c < 3; c++) {
        {
            GSP g{};
            g.srcA = word;
            g.BH = wihFH; g.BL = wihFL; g.bias = biasF; g.out = gchF;
            g.BH2 = wihBH; g.BL2 = wihBL; g.bias2 = biasB; g.out2 = gchB;
            g.slen = slen;
            g.K = 768; g.ldb = 768; g.ldc = 1536; g.c0 = c * 32;
            k_gemm_sp<5, 1><<<dim3(12, 64, 2), 256, 0, stream>>>(g);
        }
        k_lstm_rows<<<128, 384, 0, stream>>>(gchF, gchB, wpF, wpB,
                                             hbuf, cbuf, Hsf, slen, c * 32);
    }

    // ---- attention scores (split-bf16 MFMA, 12-slot deterministic partials)
    {
        GSP g{};
        g.srcA = Hsf; g.BH = s1H; g.BL = s1L; g.bias = s1b; g.s2v = s2W;
        g.escoreP = escoreP;
        g.K = 768; g.ldb = 768; g.ldc = 768; g.c0 = 0;
        k_gemm_sp<0, 3><<<dim3(6, 192), 256, 0, stream>>>(g);
    }
    k_alpha_u<<<256, 256, 0, stream>>>(escoreP, Hsf, slen, Uf);
    k_ucat<<<(384 * 768 + 255) / 256, 256, 0, stream>>>(Uf, cau, emo, UcatF);

    // ---- Cu / E = lrelu(U[idx] @ rep + b)  (f32)
    {
        G32 g{};
        g.A = UcatF; g.B = repT; g.bias = repb; g.out = CuEf;
        g.M = 384; g.N = 768; g.K = 768; g.lda = 768; g.ldb = 768; g.ldc = 768;
        k_gemm32<2><<<dim3(6, 3), 512, 0, stream>>>(g);
    }

    // ---- chunk attention
    k_chunk_sc<<<8192, 256, 0, stream>>>(CuEf, scF);
    k_chunk_emb<<<(8192 * 768 + 255) / 256, 256, 0, stream>>>(scF, CuEf, ceF);

    // ---- phase 2
    k_nrm2<<<8192, 256, 0, stream>>>(ceF, CuEf, nrm2F);
    {
        G32 g{};
        g.A = CuEf + (size_t)256 * 768; g.B = W2aT; g.out = E2F;
        g.M = 128; g.N = 768; g.K = 768; g.lda = 768; g.ldb = 768; g.ldc = 768;
        k_gemm32<0><<<dim3(6, 1), 512, 0, stream>>>(g);
    }
    {
        GSP g{};
        g.BH = B2H; g.BL = B2L; g.out = z2F; g.bias = W2b;
        g.addE = E2F; g.nrm = nrm2F; g.wn = W2W + (size_t)1536 * 768;
        g.ce = ceF; g.CuEf = CuEf; g.pos = pos;
        g.K = 1600; g.ldb = 1600; g.ldc = 768;
        k_gemm_sp<4, 4><<<dim3(6, 64), 256, 0, stream>>>(g);
    }
    k_bnstats<64><<<384, 256, 0, stream>>>(z2F, mean2, rstd2);
    k_bn_head<64><<<8192, 256, 0, stream>>>(z2F, mean2, rstd2, WoW, Wob, out, outfeatF);

    // ---- phase 3
    k_nrm3<<<32768, 256, 0, stream>>>(CuEf, nrm3F);
    {
        G32 g{};
        g.A = CuEf; g.B = W3bT; g.out = Bv3F;
        g.M = 256; g.N = 768; g.K = 768; g.lda = 768; g.ldb = 768; g.ldc = 768;
        k_gemm32<0><<<dim3(6, 2), 512, 0, stream>>>(g);
    }
    k_bv3_dis<<<(256 * 768 + 255) / 256, 256, 0, stream>>>(Bv3F, dis, W3W, W3b);
    {
        G32 g{};
        g.A = CuEf + (size_t)256 * 768; g.B = W3aT; g.out = E3F;
        g.M = 128; g.N = 768; g.K = 768; g.lda = 768; g.ldb = 768; g.ldc = 768;
        k_gemm32<0><<<dim3(6, 1), 512, 0, stream>>>(g);
    }
    {
        GSP g{};
        g.BH = W3dH; g.BL = W3dL; g.out = z3F;
        g.addE = E3F; g.addB = Bv3F; g.nrm = nrm3F; g.wn = W3W + (size_t)1536 * 768;
        g.feat = outfeatF; g.wx = W3W + (size_t)2355 * 768;
        g.CuEf = CuEf;
        g.K = 768; g.ldb = 768; g.ldc = 768;
        k_gemm_sp<2, 5><<<dim3(6, 256), 256, 0, stream>>>(g);
    }
    k_bnstats<256><<<384, 256, 0, stream>>>(z3F, mean3, rstd3);
    k_bn_head<256><<<32768, 256, 0, stream>>>(z3F, mean3, rstd3, clsW, clsb, out + 16384, nullptr);

    // ---- L
    k_label<<<128, 256, 0, stream>>>(lab3, out + 81920);
}

// Round 17
// 3824.865 us; speedup vs baseline: 1.0344x; 1.0344x over previous
//
#include <hip/hip_runtime.h>
#include <cstdint>
#include <cstddef>

// ECPEC pipeline for MI355X (gfx950).
// f32 for the amplified alpha path; split-bf16 MFMA (hi+lo, ~1e-5 rel err)
// for gates/s1/z2/z3 GEMMs. R17: best-known config — R15 LSTM (unroll 4,
// 866us/chunk) + R16 fused F+B gate GEMM launch.

#define DEV __device__ __forceinline__
typedef float f32x4 __attribute__((ext_vector_type(4)));
typedef __bf16 bf16;
typedef bf16 bf16x8 __attribute__((ext_vector_type(8)));

// ---------------------------------------------------------------- f32 GEMM (small/amplified paths)
struct G32 {
    const float* A;
    const float* B;
    float* out;
    const float* bias;
    int M, N, K, lda, ldb, ldc;
};

template <int EPI>  // 0: acc(+bias?) ; 2: lrelu(acc+bias)
__global__ __launch_bounds__(512) void k_gemm32(G32 p) {
    __shared__ __align__(16) float As[32][132];
    __shared__ __align__(16) float Bs[32][132];
    const int tid = threadIdx.x;
    const int tx = tid & 15, ty = tid >> 4;
    const int m0 = blockIdx.y * 128, n0 = blockIdx.x * 128;
    float acc[4][8] = {};
    const int ra = tid >> 2;
    const int ka = (tid & 3) * 8;

    const float* arow = p.A + (size_t)(m0 + ra) * p.lda;
    const float* brow = p.B + (size_t)(n0 + ra) * p.ldb;

    auto load_tile = [&](int kt, float* av, float* bv) {
        const float* ap = arow + kt + ka;
#pragma unroll
        for (int q = 0; q < 8; q++) av[q] = ap[q];
        const float* bp = brow + kt + ka;
#pragma unroll
        for (int q = 0; q < 8; q++) bv[q] = bp[q];
    };

    const int nt = p.K / 32;
    float av[8], bv[8];
    load_tile(0, av, bv);
    for (int t = 0; t < nt; t++) {
        __syncthreads();
#pragma unroll
        for (int q = 0; q < 8; q++) {
            As[ka + q][ra] = av[q];
            Bs[ka + q][ra] = bv[q];
        }
        __syncthreads();
        if (t + 1 < nt) load_tile((t + 1) * 32, av, bv);
#pragma unroll
        for (int kk = 0; kk < 32; kk++) {
            float a[4], b[8];
            *(f32x4*)a = *(const f32x4*)&As[kk][ty * 4];
            *(f32x4*)b = *(const f32x4*)&Bs[kk][tx * 4];
            *(f32x4*)(b + 4) = *(const f32x4*)&Bs[kk][64 + tx * 4];
#pragma unroll
            for (int i = 0; i < 4; i++)
#pragma unroll
                for (int j = 0; j < 8; j++) acc[i][j] += a[i] * b[j];
        }
    }

#pragma unroll
    for (int i = 0; i < 4; i++)
#pragma unroll
        for (int j = 0; j < 8; j++) {
            int m = m0 + ty * 4 + i;
            int n = n0 + ((j < 4) ? tx * 4 + j : 64 + tx * 4 + (j - 4));
            float x = acc[i][j];
            if constexpr (EPI == 0) {
                if (p.bias) x += p.bias[n];
            } else if constexpr (EPI == 2) {
                x += p.bias[n];
                x = x > 0.f ? x : 0.01f * x;
            }
            p.out[(size_t)m * p.ldc + n] = x;
        }
}

// ---------------------------------------------------------------- split-bf16 MFMA GEMM
// C = A @ B^T, A/B split hi/lo bf16: ab ~= AhBh + AlBh + AhBl (f32 acc).
// Tile 128x128, BK=32, 256 threads (4 waves 2x2), 4x4 16x16x32 frags.
// AMODE: 0 plain f32 A (lda=768) ; 2 A=E[e]*Cu[j] ; 4 phase-2 fold ;
//        5 fused gate GEMM (blockIdx.z: 0=fwd, 1=rev; second ptr set)
// EPI: 1 acc+bias ; 3 score partials [M][12] ; 4 phase-2 ; 5 phase-3
struct GSP {
    const float* srcA;
    const bf16* BH;
    const bf16* BL;
    float* out;
    const float* bias;
    const bf16* BH2;     // AMODE 5 (z=1)
    const bf16* BL2;
    float* out2;
    const float* bias2;
    const float* s2v;
    float* escoreP;      // [M][12] (EPI 3)
    const float* addE;
    const float* addB;
    const float* nrm;
    const float* wn;
    const float* feat;
    const float* wx;
    const float* ce;
    const float* CuEf;
    const float* pos;
    const int* slen;
    int K, ldb, ldc, c0;
};

template <int AMODE, int EPI>
__global__ __launch_bounds__(256) void k_gemm_sp(GSP p) {
    __shared__ __align__(16) bf16 AhS[128 * 32];
    __shared__ __align__(16) bf16 AlS[128 * 32];
    __shared__ __align__(16) bf16 BhS[128 * 32];
    __shared__ __align__(16) bf16 BlS[128 * 32];
    const int tid = threadIdx.x;
    const int lane = tid & 63;
    const int w = tid >> 6;
    const int wm = w >> 1, wn_ = w & 1;
    const int m0 = blockIdx.y * 128, n0 = blockIdx.x * 128;
    const int l15 = lane & 15, lq = lane >> 4;
    const int dz = (AMODE == 5) ? blockIdx.z : 0;

    const bf16* BHp = (AMODE == 5 && dz) ? p.BH2 : p.BH;
    const bf16* BLp = (AMODE == 5 && dz) ? p.BL2 : p.BL;
    const float* biasp = (AMODE == 5 && dz) ? p.bias2 : p.bias;
    float* outp = (AMODE == 5 && dz) ? p.out2 : p.out;

    f32x4 zero4 = {0.f, 0.f, 0.f, 0.f};
    f32x4 acc[4][4];
#pragma unroll
    for (int i = 0; i < 4; i++)
#pragma unroll
        for (int j = 0; j < 4; j++) acc[i][j] = zero4;

    const int c0s = tid, c1s = tid + 256;
    const int ar0 = c0s >> 2, ao0 = (c0s & 3) << 3;
    const int ar1 = c1s >> 2, ao1 = (c1s & 3) << 3;
    const int gm0 = m0 + ar0, gm1 = m0 + ar1;

    const float* arow0 = nullptr;
    const float* arow1 = nullptr;
    const float *er0 = nullptr, *cr0 = nullptr, *pr0 = nullptr;
    const float *er1 = nullptr, *cr1 = nullptr, *pr1 = nullptr;
    if constexpr (AMODE == 0) {
        arow0 = p.srcA + (size_t)gm0 * 768;
        arow1 = p.srcA + (size_t)gm1 * 768;
    } else if constexpr (AMODE == 5) {
        int b0 = gm0 >> 5, t0 = p.c0 + (gm0 & 31);
        int b1 = gm1 >> 5, t1 = p.c0 + (gm1 & 31);
        if (dz) {
            int len0 = p.slen[b0], len1 = p.slen[b1];
            t0 = (t0 < len0) ? len0 - 1 - t0 : t0;
            t1 = (t1 < len1) ? len1 - 1 - t1 : t1;
        }
        arow0 = p.srcA + ((size_t)b0 * 96 + t0) * 768;
        arow1 = p.srcA + ((size_t)b1 * 96 + t1) * 768;
    } else if constexpr (AMODE == 2) {
        er0 = p.CuEf + (size_t)(256 + (gm0 >> 8)) * 768;
        cr0 = p.CuEf + (size_t)(gm0 & 255) * 768;
        er1 = p.CuEf + (size_t)(256 + (gm1 >> 8)) * 768;
        cr1 = p.CuEf + (size_t)(gm1 & 255) * 768;
    } else {
        er0 = p.CuEf + (size_t)(256 + (gm0 >> 6)) * 768;
        cr0 = p.ce + (size_t)gm0 * 768;
        pr0 = p.pos + (size_t)gm0 * 50;
        er1 = p.CuEf + (size_t)(256 + (gm1 >> 6)) * 768;
        cr1 = p.ce + (size_t)gm1 * 768;
        pr1 = p.pos + (size_t)gm1 * 50;
    }
    const bf16* bh0 = BHp + (size_t)(n0 + ar0) * p.ldb;
    const bf16* bl0 = BLp + (size_t)(n0 + ar0) * p.ldb;
    const bf16* bh1 = BHp + (size_t)(n0 + ar1) * p.ldb;
    const bf16* bl1 = BLp + (size_t)(n0 + ar1) * p.ldb;

    auto loadA = [&](int kt, int ao, const float* arow, const float* er,
                     const float* cr, const float* pr, float* a) {
        if constexpr (AMODE == 0 || AMODE == 5) {
#pragma unroll
            for (int q = 0; q < 8; q++) a[q] = arow[kt + ao + q];
        } else if constexpr (AMODE == 2) {
#pragma unroll
            for (int q = 0; q < 8; q++) a[q] = er[kt + ao + q] * cr[kt + ao + q];
        } else {
#pragma unroll
            for (int q = 0; q < 8; q++) {
                int k = kt + ao + q;
                float v;
                if (k < 768) v = cr[k];
                else if (k < 1536) v = er[k - 768] * cr[k - 768];
                else if (k < 1586) v = pr[k - 1536];
                else v = 0.f;
                a[q] = v;
            }
        }
    };

    const int nt = p.K / 32;
    float a0f[8], a1f[8];
    bf16x8 b0h, b0l, b1h, b1l;
    auto load_tile = [&](int kt) {
        loadA(kt, ao0, arow0, er0, cr0, pr0, a0f);
        loadA(kt, ao1, arow1, er1, cr1, pr1, a1f);
        b0h = *(const bf16x8*)(bh0 + kt + ao0);
        b0l = *(const bf16x8*)(bl0 + kt + ao0);
        b1h = *(const bf16x8*)(bh1 + kt + ao1);
        b1l = *(const bf16x8*)(bl1 + kt + ao1);
    };

    load_tile(0);
    for (int t = 0; t < nt; t++) {
        __syncthreads();
        {
            bf16x8 h8, l8;
#pragma unroll
            for (int q = 0; q < 8; q++) {
                bf16 h = (bf16)a0f[q];
                h8[q] = h;
                l8[q] = (bf16)(a0f[q] - (float)h);
            }
            *(bf16x8*)(AhS + (c0s << 3)) = h8;
            *(bf16x8*)(AlS + (c0s << 3)) = l8;
#pragma unroll
            for (int q = 0; q < 8; q++) {
                bf16 h = (bf16)a1f[q];
                h8[q] = h;
                l8[q] = (bf16)(a1f[q] - (float)h);
            }
            *(bf16x8*)(AhS + (c1s << 3)) = h8;
            *(bf16x8*)(AlS + (c1s << 3)) = l8;
            *(bf16x8*)(BhS + (c0s << 3)) = b0h;
            *(bf16x8*)(BlS + (c0s << 3)) = b0l;
            *(bf16x8*)(BhS + (c1s << 3)) = b1h;
            *(bf16x8*)(BlS + (c1s << 3)) = b1l;
        }
        __syncthreads();
        if (t + 1 < nt) load_tile((t + 1) * 32);

        bf16x8 ah[4], bh[4], xl[4];
#pragma unroll
        for (int i = 0; i < 4; i++) {
            ah[i] = *(const bf16x8*)(AhS + (wm * 64 + i * 16 + l15) * 32 + (lq << 3));
            bh[i] = *(const bf16x8*)(BhS + (wn_ * 64 + i * 16 + l15) * 32 + (lq << 3));
        }
#pragma unroll
        for (int i = 0; i < 4; i++)
#pragma unroll
            for (int j = 0; j < 4; j++)
                acc[i][j] = __builtin_amdgcn_mfma_f32_16x16x32_bf16(ah[i], bh[j], acc[i][j], 0, 0, 0);
#pragma unroll
        for (int i = 0; i < 4; i++)
            xl[i] = *(const bf16x8*)(AlS + (wm * 64 + i * 16 + l15) * 32 + (lq << 3));
#pragma unroll
        for (int i = 0; i < 4; i++)
#pragma unroll
            for (int j = 0; j < 4; j++)
                acc[i][j] = __builtin_amdgcn_mfma_f32_16x16x32_bf16(xl[i], bh[j], acc[i][j], 0, 0, 0);
#pragma unroll
        for (int i = 0; i < 4; i++)
            xl[i] = *(const bf16x8*)(BlS + (wn_ * 64 + i * 16 + l15) * 32 + (lq << 3));
#pragma unroll
        for (int i = 0; i < 4; i++)
#pragma unroll
            for (int j = 0; j < 4; j++)
                acc[i][j] = __builtin_amdgcn_mfma_f32_16x16x32_bf16(ah[i], xl[j], acc[i][j], 0, 0, 0);
    }

    if constexpr (EPI == 3) {
#pragma unroll
        for (int i = 0; i < 4; i++)
#pragma unroll
            for (int r = 0; r < 4; r++) {
                float s = 0.f;
#pragma unroll
                for (int j = 0; j < 4; j++) {
                    int n = n0 + wn_ * 64 + j * 16 + l15;
                    float v = acc[i][j][r] + biasp[n];
                    v = v > 0.f ? v : 0.01f * v;
                    s += v * p.s2v[n];
                }
                s += __shfl_xor(s, 1);
                s += __shfl_xor(s, 2);
                s += __shfl_xor(s, 4);
                s += __shfl_xor(s, 8);
                if (l15 == 0) {
                    int m = m0 + wm * 64 + i * 16 + (lq << 2) + r;
                    p.escoreP[(size_t)m * 12 + blockIdx.x * 2 + wn_] = s;
                }
            }
    } else {
#pragma unroll
        for (int i = 0; i < 4; i++)
#pragma unroll
            for (int j = 0; j < 4; j++)
#pragma unroll
                for (int r = 0; r < 4; r++) {
                    int m = m0 + wm * 64 + i * 16 + (lq << 2) + r;
                    int n = n0 + wn_ * 64 + j * 16 + l15;
                    float v = acc[i][j][r];
                    if constexpr (EPI == 1) {
                        v += biasp[n];
                    } else if constexpr (EPI == 4) {
                        int e = m >> 6;
                        v += p.addE[(size_t)e * 768 + n] + p.nrm[m] * p.wn[n] + p.bias[n];
                    } else if constexpr (EPI == 5) {
                        int e = m >> 8, jj = m & 255;
                        float ex = p.feat[e * 64 + (jj >> 2)];
                        v += p.addE[(size_t)e * 768 + n] + p.addB[(size_t)jj * 768 + n] +
                             p.nrm[m] * p.wn[n] + ex * p.wx[n];
                    }
                    outp[(size_t)m * p.ldc + n] = v;
                }
    }
}

// ---------------------------------------------------------------- Whh pack
__global__ void k_wpack(const float* __restrict__ whh, float* __restrict__ wp) {
    int idx = blockIdx.x * 256 + threadIdx.x;
    if (idx < 384 * 1536) {
        int k = idx / 1536, rem = idx - k * 1536;
        int u = rem >> 2, g = rem & 3;
        wp[idx] = whh[(size_t)(g * 384 + u) * 384 + k];
    }
}

// ---------------------------------------------------------------- LSTM rows (R10/R13/R15, proven)
// 384 threads (thread = unit u), 4 rows of ONE direction, 32 steps, h in LDS,
// c in registers, no inter-block sync. dir = blockIdx&1 (XCD L2 wp affinity).
__global__ __launch_bounds__(384) void k_lstm_rows(
    const float* __restrict__ gchF, const float* __restrict__ gchB,
    const float* __restrict__ wpF, const float* __restrict__ wpB,
    float* __restrict__ hbuf, float* __restrict__ cbuf, float* __restrict__ Hs,
    const int* __restrict__ slen, int c0) {
    __shared__ __align__(16) float hlds[4][384];
    const int tid = threadIdx.x;
    const int dir = blockIdx.x & 1;
    const int r0 = (blockIdx.x >> 1) * 4;
    const float* gch = dir ? gchB : gchF;
    const float* wp = dir ? wpB : wpF;
    float* hb = hbuf + (size_t)dir * 98304;
    float* cb = cbuf + (size_t)dir * 98304;
    const int u = tid;

    {
        int r = tid / 96, c4 = (tid - r * 96) * 4;
        *(f32x4*)&hlds[r][c4] = *(const f32x4*)&hb[(size_t)(r0 + r) * 384 + c4];
    }
    float c_[4];
    int len_[4];
#pragma unroll
    for (int r = 0; r < 4; r++) {
        c_[r] = cb[(size_t)(r0 + r) * 384 + u];
        len_[r] = slen[r0 + r];
    }
    __syncthreads();

    const float* wpb = wp + (size_t)u * 4;
    for (int t = c0; t < c0 + 32; t++) {
        float acc[4][4] = {};
#pragma unroll 4
        for (int k = 0; k < 384; k++) {
            f32x4 wv = *(const f32x4*)(wpb + (size_t)k * 1536);
            float h0 = hlds[0][k], h1 = hlds[1][k];
            float h2 = hlds[2][k], h3 = hlds[3][k];
#pragma unroll
            for (int g = 0; g < 4; g++) {
                acc[0][g] += h0 * wv[g];
                acc[1][g] += h1 * wv[g];
                acc[2][g] += h2 * wv[g];
                acc[3][g] += h3 * wv[g];
            }
        }
        __syncthreads();
#pragma unroll
        for (int r = 0; r < 4; r++) {
            int bg = r0 + r;
            int len = len_[r];
            int tsrc = dir ? (t < len ? len - 1 - t : t) : t;
            const float* gp = gch + (((size_t)bg << 5) + (t & 31)) * 1536;
            float gi = acc[r][0] + gp[u];
            float gf = acc[r][1] + gp[384 + u];
            float gg2 = acc[r][2] + gp[768 + u];
            float go = acc[r][3] + gp[1152 + u];
            float si = 1.f / (1.f + __expf(-gi));
            float sf = 1.f / (1.f + __expf(-gf));
            float so = 1.f / (1.f + __expf(-go));
            float tg = tanhf(gg2);
            float cn = sf * c_[r] + si * tg;
            float hn = so * tanhf(cn);
            c_[r] = cn;
            hlds[r][u] = hn;
            int tpos = dir ? tsrc : t;
            Hs[((size_t)bg * 96 + tpos) * 768 + dir * 384 + u] = hn;
        }
        __syncthreads();
    }

    {
        int r = tid / 96, c4 = (tid - r * 96) * 4;
        *(f32x4*)&hb[(size_t)(r0 + r) * 384 + c4] = *(const f32x4*)&hlds[r][c4];
    }
#pragma unroll
    for (int r = 0; r < 4; r++) cb[(size_t)(r0 + r) * 384 + u] = c_[r];
}

// ---------------------------------------------------------------- small kernels
__global__ void k_bias2(const float* a, const float* b, float* o, int n) {
    int i = blockIdx.x * 256 + threadIdx.x;
    if (i < n) o[i] = a[i] + b[i];
}

__global__ void k_splitw(const float* __restrict__ src, bf16* __restrict__ hi,
                         bf16* __restrict__ lo, int n) {
    int i = blockIdx.x * 256 + threadIdx.x;
    if (i < n) {
        float v = src[i];
        bf16 h = (bf16)v;
        hi[i] = h;
        lo[i] = (bf16)(v - (float)h);
    }
}

__global__ __launch_bounds__(256) void k_transp32(const float* __restrict__ src,
                                                  float* __restrict__ dst, int roff) {
    __shared__ float tile[32][33];
    int tx = threadIdx.x & 31, ty = threadIdx.x >> 5;
    int n0 = blockIdx.x * 32, k0 = blockIdx.y * 32;
#pragma unroll
    for (int r = ty; r < 32; r += 8)
        tile[r][tx] = src[(size_t)(roff + k0 + r) * 768 + n0 + tx];
    __syncthreads();
#pragma unroll
    for (int r = ty; r < 32; r += 8)
        dst[(size_t)(n0 + r) * 768 + k0 + tx] = tile[tx][r];
}

__global__ __launch_bounds__(256) void k_transp_sp(const float* __restrict__ src,
                                                   bf16* __restrict__ hi,
                                                   bf16* __restrict__ lo, int roff) {
    __shared__ float tile[32][33];
    int tx = threadIdx.x & 31, ty = threadIdx.x >> 5;
    int n0 = blockIdx.x * 32, k0 = blockIdx.y * 32;
#pragma unroll
    for (int r = ty; r < 32; r += 8)
        tile[r][tx] = src[(size_t)(roff + k0 + r) * 768 + n0 + tx];
    __syncthreads();
#pragma unroll
    for (int r = ty; r < 32; r += 8) {
        float v = tile[tx][r];
        bf16 h = (bf16)v;
        hi[(size_t)(n0 + r) * 768 + k0 + tx] = h;
        lo[(size_t)(n0 + r) * 768 + k0 + tx] = (bf16)(v - (float)h);
    }
}

__global__ __launch_bounds__(256) void k_b2cat_sp(const float* __restrict__ W2,
                                                  bf16* __restrict__ hi,
                                                  bf16* __restrict__ lo) {
    __shared__ float tile[32][33];
    int tx = threadIdx.x & 31, ty = threadIdx.x >> 5;
    int n0 = blockIdx.x * 32, k0 = blockIdx.y * 32;
#pragma unroll
    for (int r = ty; r < 32; r += 8) {
        int k = k0 + r;
        float v = 0.f;
        if (k < 1586) {
            int sr = (k < 768) ? 768 + k : 769 + k;
            v = W2[(size_t)sr * 768 + n0 + tx];
        }
        tile[r][tx] = v;
    }
    __syncthreads();
#pragma unroll
    for (int r = ty; r < 32; r += 8) {
        float v = tile[tx][r];
        bf16 h = (bf16)v;
        hi[(size_t)(n0 + r) * 1600 + k0 + tx] = h;
        lo[(size_t)(n0 + r) * 1600 + k0 + tx] = (bf16)(v - (float)h);
    }
}

// alpha = e*mask / (sum + 1e-9); U[b,:] = sum_t alpha[t]*Hs[b,t,:]
__global__ __launch_bounds__(256) void k_alpha_u(const float* __restrict__ escoreP,
                                                 const float* __restrict__ Hs,
                                                 const int* __restrict__ slen,
                                                 float* __restrict__ U) {
    __shared__ float al[96];
    __shared__ float dsh;
    int b = blockIdx.x, tid = threadIdx.x;
    int len = slen[b];
    if (tid < 96) {
        const float* ep = escoreP + (size_t)(b * 96 + tid) * 12;
        float e = 0.f;
#pragma unroll
        for (int q = 0; q < 12; q++) e += ep[q];
        al[tid] = (tid < len) ? e : 0.f;
    }
    __syncthreads();
    if (tid == 0) {
        float s = 0.f;
        for (int i = 0; i < 96; i++) s += al[i];
        dsh = 1.f / (s + 1e-9f);
    }
    __syncthreads();
    float dinv = dsh;
    for (int d = tid; d < 768; d += 256) {
        float acc = 0.f;
        const float* hp = Hs + (size_t)b * 96 * 768 + d;
        for (int tt = 0; tt < 96; tt++) acc += al[tt] * hp[(size_t)tt * 768];
        U[(size_t)b * 768 + d] = acc * dinv;
    }
}

__global__ void k_ucat(const float* __restrict__ U, const int* __restrict__ cau,
                       const int* __restrict__ emo, float* __restrict__ Ucat) {
    int i = blockIdx.x * 256 + threadIdx.x;
    if (i < 384 * 768) {
        int r = i / 768, d = i - r * 768;
        int src = (r < 256) ? cau[r] : emo[r - 256];
        Ucat[i] = U[(size_t)src * 768 + d];
    }
}

__global__ __launch_bounds__(256) void k_chunk_sc(const float* __restrict__ CuEf,
                                                  float* __restrict__ sc) {
    int m = blockIdx.x;
    int e = m >> 6, nk = m & 63;
    int tid = threadIdx.x, w = tid >> 6, lane = tid & 63;
    const float* Er = CuEf + (size_t)(256 + e) * 768;
    const float* Cr = CuEf + (size_t)(nk * 4 + w) * 768;
    float acc = 0.f;
    for (int q = lane; q < 768; q += 64) acc += Er[q] * Cr[q];
    for (int off = 32; off; off >>= 1) acc += __shfl_xor(acc, off);
    __shared__ float S[4];
    if (lane == 0) S[w] = acc;
    __syncthreads();
    if (tid == 0) {
        float mx = fmaxf(fmaxf(S[0], S[1]), fmaxf(S[2], S[3]));
        float e0 = expf(S[0] - mx), e1 = expf(S[1] - mx), e2 = expf(S[2] - mx),
              e3 = expf(S[3] - mx);
        float inv = 1.f / (e0 + e1 + e2 + e3);
        sc[4 * m] = e0 * inv; sc[4 * m + 1] = e1 * inv;
        sc[4 * m + 2] = e2 * inv; sc[4 * m + 3] = e3 * inv;
    }
}

__global__ void k_chunk_emb(const float* __restrict__ sc, const float* __restrict__ CuEf,
                            float* __restrict__ ce) {
    int i = blockIdx.x * 256 + threadIdx.x;
    if (i < 8192 * 768) {
        int m = i / 768, d = i - m * 768;
        int nk = m & 63;
        const float* base = CuEf + (size_t)(nk * 4) * 768 + d;
        ce[i] = sc[4 * m] * base[0] + sc[4 * m + 1] * base[768] +
                sc[4 * m + 2] * base[1536] + sc[4 * m + 3] * base[2304];
    }
}

__global__ __launch_bounds__(256) void k_nrm2(const float* __restrict__ ce,
                                              const float* __restrict__ CuEf,
                                              float* __restrict__ nrm2) {
    int m = blockIdx.x, tid = threadIdx.x;
    int e = m >> 6;
    const float* cr = ce + (size_t)m * 768;
    const float* er = CuEf + (size_t)(256 + e) * 768;
    float ss = 0.f;
    for (int d = tid; d < 768; d += 256) {
        float df = er[d] - cr[d];
        ss += df * df;
    }
    for (int off = 32; off; off >>= 1) ss += __shfl_xor(ss, off);
    __shared__ float red[4];
    if ((tid & 63) == 0) red[tid >> 6] = ss;
    __syncthreads();
    if (tid == 0) nrm2[m] = sqrtf(red[0] + red[1] + red[2] + red[3]);
}

__global__ __launch_bounds__(256) void k_nrm3(const float* __restrict__ CuEf,
                                              float* __restrict__ nrm3) {
    int m = blockIdx.x, tid = threadIdx.x;
    int e = m >> 8, j = m & 255;
    const float* cu = CuEf + (size_t)j * 768;
    const float* er = CuEf + (size_t)(256 + e) * 768;
    float ss = 0.f;
    for (int d = tid; d < 768; d += 256) {
        float df = er[d] - cu[d];
        ss += df * df;
    }
    for (int off = 32; off; off >>= 1) ss += __shfl_xor(ss, off);
    __shared__ float red[4];
    if ((tid & 63) == 0) red[tid >> 6] = ss;
    __syncthreads();
    if (tid == 0) nrm3[m] = sqrtf(red[0] + red[1] + red[2] + red[3]);
}

__global__ void k_bv3_dis(float* __restrict__ Bv3, const float* __restrict__ dis,
                          const float* __restrict__ W3, const float* __restrict__ b3) {
    int i = blockIdx.x * 256 + threadIdx.x;
    if (i < 256 * 768) {
        int j = i / 768, n = i - j * 768;
        float s = Bv3[i] + b3[n];
        const float* dr = dis + j * 50;
#pragma unroll 10
        for (int q = 0; q < 50; q++) s += dr[q] * W3[(size_t)(2305 + q) * 768 + n];
        Bv3[i] = s;
    }
}

template <int GROUP>
__global__ __launch_bounds__(256) void k_bnstats(const float* __restrict__ z,
                                                 float* __restrict__ mean,
                                                 float* __restrict__ rstd) {
    int idx = blockIdx.x * 256 + threadIdx.x;
    if (idx >= 128 * 768) return;
    int e = idx / 768, n = idx - e * 768;
    const float* p = z + (size_t)e * GROUP * 768 + n;
    float s = 0.f;
    for (int k = 0; k < GROUP; k++) s += p[(size_t)k * 768];
    float mu = s * (1.f / GROUP);
    float q = 0.f;
    for (int k = 0; k < GROUP; k++) {
        float d = p[(size_t)k * 768] - mu;
        q += d * d;
    }
    mean[idx] = mu;
    rstd[idx] = rsqrtf(q * (1.f / GROUP) + 1e-5f);
}

template <int GROUP>
__global__ __launch_bounds__(256) void k_bn_head(const float* __restrict__ z,
                                                 const float* __restrict__ mean,
                                                 const float* __restrict__ rstd,
                                                 const float* __restrict__ W,
                                                 const float* __restrict__ bb,
                                                 float* __restrict__ outp,
                                                 float* __restrict__ feat) {
    int m = blockIdx.x;
    int e = m / GROUP;
    int tid = threadIdx.x;
    float a0 = 0.f, a1 = 0.f;
    const float* zr = z + (size_t)m * 768;
    const float* mr = mean + (size_t)e * 768;
    const float* rr = rstd + (size_t)e * 768;
    for (int n = tid; n < 768; n += 256) {
        float h = (zr[n] - mr[n]) * rr[n];
        h = h > 0.f ? h : 0.01f * h;
        a0 += h * W[2 * n];
        a1 += h * W[2 * n + 1];
    }
    for (int off = 32; off; off >>= 1) {
        a0 += __shfl_xor(a0, off);
        a1 += __shfl_xor(a1, off);
    }
    __shared__ float s0[4], s1v[4];
    int w = tid >> 6;
    if ((tid & 63) == 0) { s0[w] = a0; s1v[w] = a1; }
    __syncthreads();
    if (tid == 0) {
        float l0 = s0[0] + s0[1] + s0[2] + s0[3] + bb[0];
        float l1 = s1v[0] + s1v[1] + s1v[2] + s1v[3] + bb[1];
        float mx = fmaxf(l0, l1);
        float ls = mx + logf(expf(l0 - mx) + expf(l1 - mx));
        outp[2 * m] = l0 - ls;
        outp[2 * m + 1] = l1 - ls;
        if (feat) feat[m] = (l1 > l0) ? 1.f : 0.f;
    }
}

__global__ void k_label(const int* __restrict__ l3, float* __restrict__ out) {
    int e = blockIdx.x, c = threadIdx.x;
    int a = l3[e * 3], b = l3[e * 3 + 1], d = l3[e * 3 + 2];
    out[e * 256 + c] = (a == c || b == c || d == c) ? 1.f : 0.f;
}

// ---------------------------------------------------------------- host
extern "C" void kernel_launch(void* const* d_in, const int* in_sizes, int n_in,
                              void* d_out, int out_size, void* d_ws, size_t ws_size,
                              hipStream_t stream) {
    (void)in_sizes; (void)n_in; (void)out_size; (void)ws_size;
    const float* word = (const float*)d_in[0];
    const float* pos = (const float*)d_in[1];
    const float* dis = (const float*)d_in[2];
    const float* WihF = (const float*)d_in[3];
    const float* WhhF = (const float*)d_in[4];
    const float* bihF = (const float*)d_in[5];
    const float* bhhF = (const float*)d_in[6];
    const float* WihB = (const float*)d_in[7];
    const float* WhhB = (const float*)d_in[8];
    const float* bihB = (const float*)d_in[9];
    const float* bhhB = (const float*)d_in[10];
    const float* s1W = (const float*)d_in[11];
    const float* s1b = (const float*)d_in[12];
    const float* s2W = (const float*)d_in[13];
    const float* repW = (const float*)d_in[14];
    const float* repb = (const float*)d_in[15];
    const float* W2W = (const float*)d_in[16];
    const float* W2b = (const float*)d_in[17];
    const float* WoW = (const float*)d_in[18];
    const float* Wob = (const float*)d_in[19];
    const float* W3W = (const float*)d_in[20];
    const float* W3b = (const float*)d_in[21];
    const float* clsW = (const float*)d_in[22];
    const float* clsb = (const float*)d_in[23];
    const int* slen = (const int*)d_in[24];
    const int* emo = (const int*)d_in[25];
    const int* cau = (const int*)d_in[26];
    const int* lab3 = (const int*)d_in[27];
    float* out = (float*)d_out;

    char* ws = (char*)d_ws;
    size_t off = 0;
    auto alloc = [&](size_t b) -> char* {
        char* p = ws + off;
        off += (b + 255) & ~(size_t)255;
        return p;
    };
    float* biasF = (float*)alloc(1536 * 4);
    float* biasB = (float*)alloc(1536 * 4);
    float* wpF = (float*)alloc((size_t)384 * 1536 * 4);
    float* wpB = (float*)alloc((size_t)384 * 1536 * 4);
    bf16* wihFH = (bf16*)alloc((size_t)1536 * 768 * 2);
    bf16* wihFL = (bf16*)alloc((size_t)1536 * 768 * 2);
    bf16* wihBH = (bf16*)alloc((size_t)1536 * 768 * 2);
    bf16* wihBL = (bf16*)alloc((size_t)1536 * 768 * 2);
    bf16* s1H = (bf16*)alloc((size_t)768 * 768 * 2);
    bf16* s1L = (bf16*)alloc((size_t)768 * 768 * 2);
    bf16* B2H = (bf16*)alloc((size_t)768 * 1600 * 2);
    bf16* B2L = (bf16*)alloc((size_t)768 * 1600 * 2);
    bf16* W3dH = (bf16*)alloc((size_t)768 * 768 * 2);
    bf16* W3dL = (bf16*)alloc((size_t)768 * 768 * 2);
    float* repT = (float*)alloc((size_t)768 * 768 * 4);
    float* W2aT = (float*)alloc((size_t)768 * 768 * 4);
    float* W3aT = (float*)alloc((size_t)768 * 768 * 4);
    float* W3bT = (float*)alloc((size_t)768 * 768 * 4);
    float* hbuf = (float*)alloc((size_t)2 * 98304 * 4);
    float* cbuf = (float*)alloc((size_t)2 * 98304 * 4);
    float* Hsf = (float*)alloc((size_t)24576 * 768 * 4);
    float* escoreP = (float*)alloc((size_t)24576 * 12 * 4);
    float* Uf = (float*)alloc((size_t)256 * 768 * 4);
    float* UcatF = (float*)alloc((size_t)384 * 768 * 4);
    float* CuEf = (float*)alloc((size_t)384 * 768 * 4);
    float* scF = (float*)alloc((size_t)8192 * 4 * 4);
    float* nrm2F = (float*)alloc(8192 * 4);
    float* nrm3F = (float*)alloc(32768 * 4);
    float* E2F = (float*)alloc((size_t)128 * 768 * 4);
    float* E3F = (float*)alloc((size_t)128 * 768 * 4);
    float* Bv3F = (float*)alloc((size_t)256 * 768 * 4);
    float* mean2 = (float*)alloc((size_t)128 * 768 * 4);
    float* rstd2 = (float*)alloc((size_t)128 * 768 * 4);
    float* mean3 = (float*)alloc((size_t)128 * 768 * 4);
    float* rstd3 = (float*)alloc((size_t)128 * 768 * 4);
    float* outfeatF = (float*)alloc(8192 * 4);
    char* BIG = alloc((size_t)103 * 1024 * 1024);

    float* gchF = (float*)BIG;
    float* gchB = (float*)(BIG + (size_t)50331648);
    float* ceF = (float*)BIG;
    float* z2F = (float*)(BIG + (size_t)25165824);
    float* z3F = (float*)BIG;

    // ---- init h0 = c0 = 0
    hipMemsetAsync(hbuf, 0, (size_t)4 * 98304 * 4, stream);

    // ---- weight prep
    k_bias2<<<6, 256, 0, stream>>>(bihF, bhhF, biasF, 1536);
    k_bias2<<<6, 256, 0, stream>>>(bihB, bhhB, biasB, 1536);
    k_wpack<<<2304, 256, 0, stream>>>(WhhF, wpF);
    k_wpack<<<2304, 256, 0, stream>>>(WhhB, wpB);
    k_splitw<<<4608, 256, 0, stream>>>(WihF, wihFH, wihFL, 1536 * 768);
    k_splitw<<<4608, 256, 0, stream>>>(WihB, wihBH, wihBL, 1536 * 768);
    k_transp_sp<<<dim3(24, 24), 256, 0, stream>>>(s1W, s1H, s1L, 0);
    k_transp32<<<dim3(24, 24), 256, 0, stream>>>(repW, repT, 0);
    k_transp32<<<dim3(24, 24), 256, 0, stream>>>(W2W, W2aT, 0);
    k_transp32<<<dim3(24, 24), 256, 0, stream>>>(W3W, W3aT, 0);
    k_transp32<<<dim3(24, 24), 256, 0, stream>>>(W3W, W3bT, 768);
    k_transp_sp<<<dim3(24, 24), 256, 0, stream>>>(W3W, W3dH, W3dL, 1537);
    k_b2cat_sp<<<dim3(24, 50), 256, 0, stream>>>(W2W, B2H, B2L);

    // ---- LSTM: 3 chunks {1 fused F+B gate GEMM + 1 sync-free row kernel}
    for (int c = 0; c < 3; c++) {
        {
            GSP g{};
            g.srcA = word;
            g.BH = wihFH; g.BL = wihFL; g.bias = biasF; g.out = gchF;
            g.BH2 = wihBH; g.BL2 = wihBL; g.bias2 = biasB; g.out2 = gchB;
            g.slen = slen;
            g.K = 768; g.ldb = 768; g.ldc = 1536; g.c0 = c * 32;
            k_gemm_sp<5, 1><<<dim3(12, 64, 2), 256, 0, stream>>>(g);
        }
        k_lstm_rows<<<128, 384, 0, stream>>>(gchF, gchB, wpF, wpB,
                                             hbuf, cbuf, Hsf, slen, c * 32);
    }

    // ---- attention scores (split-bf16 MFMA, 12-slot deterministic partials)
    {
        GSP g{};
        g.srcA = Hsf; g.BH = s1H; g.BL = s1L; g.bias = s1b; g.s2v = s2W;
        g.escoreP = escoreP;
        g.K = 768; g.ldb = 768; g.ldc = 768; g.c0 = 0;
        k_gemm_sp<0, 3><<<dim3(6, 192), 256, 0, stream>>>(g);
    }
    k_alpha_u<<<256, 256, 0, stream>>>(escoreP, Hsf, slen, Uf);
    k_ucat<<<(384 * 768 + 255) / 256, 256, 0, stream>>>(Uf, cau, emo, UcatF);

    // ---- Cu / E = lrelu(U[idx] @ rep + b)  (f32)
    {
        G32 g{};
        g.A = UcatF; g.B = repT; g.bias = repb; g.out = CuEf;
        g.M = 384; g.N = 768; g.K = 768; g.lda = 768; g.ldb = 768; g.ldc = 768;
        k_gemm32<2><<<dim3(6, 3), 512, 0, stream>>>(g);
    }

    // ---- chunk attention
    k_chunk_sc<<<8192, 256, 0, stream>>>(CuEf, scF);
    k_chunk_emb<<<(8192 * 768 + 255) / 256, 256, 0, stream>>>(scF, CuEf, ceF);

    // ---- phase 2
    k_nrm2<<<8192, 256, 0, stream>>>(ceF, CuEf, nrm2F);
    {
        G32 g{};
        g.A = CuEf + (size_t)256 * 768; g.B = W2aT; g.out = E2F;
        g.M = 128; g.N = 768; g.K = 768; g.lda = 768; g.ldb = 768; g.ldc = 768;
        k_gemm32<0><<<dim3(6, 1), 512, 0, stream>>>(g);
    }
    {
        GSP g{};
        g.BH = B2H; g.BL = B2L; g.out = z2F; g.bias = W2b;
        g.addE = E2F; g.nrm = nrm2F; g.wn = W2W + (size_t)1536 * 768;
        g.ce = ceF; g.CuEf = CuEf; g.pos = pos;
        g.K = 1600; g.ldb = 1600; g.ldc = 768;
        k_gemm_sp<4, 4><<<dim3(6, 64), 256, 0, stream>>>(g);
    }
    k_bnstats<64><<<384, 256, 0, stream>>>(z2F, mean2, rstd2);
    k_bn_head<64><<<8192, 256, 0, stream>>>(z2F, mean2, rstd2, WoW, Wob, out, outfeatF);

    // ---- phase 3
    k_nrm3<<<32768, 256, 0, stream>>>(CuEf, nrm3F);
    {
        G32 g{};
        g.A = CuEf; g.B = W3bT; g.out = Bv3F;
        g.M = 256; g.N = 768; g.K = 768; g.lda = 768; g.ldb = 768; g.ldc = 768;
        k_gemm32<0><<<dim3(6, 2), 512, 0, stream>>>(g);
    }
    k_bv3_dis<<<(256 * 768 + 255) / 256, 256, 0, stream>>>(Bv3F, dis, W3W, W3b);
    {
        G32 g{};
        g.A = CuEf + (size_t)256 * 768; g.B = W3aT; g.out = E3F;
        g.M = 128; g.N = 768; g.K = 768; g.lda = 768; g.ldb = 768; g.ldc = 768;
        k_gemm32<0><<<dim3(6, 1), 512, 0, stream>>>(g);
    }
    {
        GSP g{};
        g.BH = W3dH; g.BL = W3dL; g.out = z3F;
        g.addE = E3F; g.addB = Bv3F; g.nrm = nrm3F; g.wn = W3W + (size_t)1536 * 768;
        g.feat = outfeatF; g.wx = W3W + (size_t)2355 * 768;
        g.CuEf = CuEf;
        g.K = 768; g.ldb = 768; g.ldc = 768;
        k_gemm_sp<2, 5><<<dim3(6, 256), 256, 0, stream>>>(g);
    }
    k_bnstats<256><<<384, 256, 0, stream>>>(z3F, mean3, rstd3);
    k_bn_head<256><<<32768, 256, 0, stream>>>(z3F, mean3, rstd3, clsW, clsb, out + 16384, nullptr);

    // ---- L
    k_label<<<128, 256, 0, stream>>>(lab3, out + 81920);
}